// Round 1
// baseline (190.315 us; speedup 1.0000x reference)
//
#include <hip/hip_runtime.h>

// AttentionGroupPool: B=8192 rows, T=4096, 64 ragged groups (sizes cycle
// 32/64/96/64; cycle = 256 elems = 4 groups, 16 cycles).
// One block (256 thr) per row. Wave w at float4-iteration k covers exactly
// cycle c = w + 4k, so every group is a contiguous lane-segment of one wave:
// lanes [0,8) -> g(4c+0) [32 el], [8,24) -> g(4c+1) [64 el],
// [24,48) -> g(4c+2) [96 el], [48,64) -> g(4c+3) [64 el].
//
// v2: group sums computed fully in-register via wave shuffles (octet
// butterflies + broadcasts), spread across all 4 waves. Removes the old
// 16-way bank-conflicted serial LDS loop on wave 0. LDS: 4KB -> 256B.

#define TPB 256

__global__ __launch_bounds__(TPB) void agp_kernel(
    const float* __restrict__ H,
    const float* __restrict__ score_w,
    const float* __restrict__ score_b,
    float* __restrict__ Z,
    float* __restrict__ A,
    int T)  // = 4096
{
  const int b    = blockIdx.x;
  const int tid  = threadIdx.x;
  const int lane = tid & 63;
  const int w    = tid >> 6;
  const float4* row = (const float4*)(H + (size_t)b * T);

  __shared__ float groups[64];   // normalized group means G[b][g]

  // Issue all 4 coalesced 16B loads up front (memory-level parallelism).
  float4 v0 = row[tid];
  float4 v1 = row[tid + TPB];
  float4 v2 = row[tid + 2 * TPB];
  float4 v3 = row[tid + 3 * TPB];

  float s[4];
  s[0] = (v0.x + v0.y) + (v0.z + v0.w);
  s[1] = (v1.x + v1.y) + (v1.z + v1.w);
  s[2] = (v2.x + v2.y) + (v2.z + v2.w);
  s[3] = (v3.x + v3.y) + (v3.z + v3.w);

  const float invsz[4] = {1.f / 32.f, 1.f / 64.f, 1.f / 96.f, 1.f / 64.f};

#pragma unroll
  for (int k = 0; k < 4; ++k) {
    // Sum within each aligned 8-lane octet (3 butterflies).
    float os = s[k];
    os += __shfl_xor(os, 1);
    os += __shfl_xor(os, 2);
    os += __shfl_xor(os, 4);

    // Broadcast the 8 octet sums; assemble the cycle's 4 group sums.
    const float o0 = __shfl(os, 0);
    const float o1 = __shfl(os, 8);
    const float o2 = __shfl(os, 16);
    const float o3 = __shfl(os, 24);
    const float o4 = __shfl(os, 32);
    const float o5 = __shfl(os, 40);
    const float o6 = __shfl(os, 48);
    const float o7 = __shfl(os, 56);

    const int c = w + 4 * k;   // cycle 0..15 handled by this wave-iter
    if (lane < 4) {
      float g = (lane == 0) ? o0
              : (lane == 1) ? (o1 + o2)
              : (lane == 2) ? ((o3 + o4) + o5)
                            : (o6 + o7);
      // 16 concurrent writes (4 waves x 4 lanes) -> addresses 4c+lane are
      // all distinct banks mod 32: conflict-free.
      groups[4 * c + lane] = g * invsz[lane];
    }
  }
  __syncthreads();

  if (tid < 64) {
    const float G = groups[tid];           // 64 consecutive floats: 2-way, free
    const float score = G * score_w[0] + score_b[0];

    // softmax over 64 groups — full-wave butterflies in wave 0
    float m = score;
#pragma unroll
    for (int mask = 32; mask >= 1; mask >>= 1)
      m = fmaxf(m, __shfl_xor(m, mask));

    const float e = __expf(score - m);
    float se = e;        // sum of exp
    float sg = e * G;    // sum of exp * G
#pragma unroll
    for (int mask = 32; mask >= 1; mask >>= 1) {
      se += __shfl_xor(se, mask);
      sg += __shfl_xor(sg, mask);
    }

    A[(size_t)b * 64 + tid] = e / se;      // coalesced 256B row write
    if (tid == 0) Z[b] = sg / se;
  }
}

extern "C" void kernel_launch(void* const* d_in, const int* in_sizes, int n_in,
                              void* d_out, int out_size, void* d_ws, size_t ws_size,
                              hipStream_t stream) {
  const float* H  = (const float*)d_in[0];
  const float* sw = (const float*)d_in[1];
  const float* sb = (const float*)d_in[2];

  const int T = 4096;
  const int B = in_sizes[0] / T;        // 8192

  float* Z = (float*)d_out;             // [B]
  float* A = Z + B;                     // [B, 64] flattened after Z

  agp_kernel<<<B, TPB, 0, stream>>>(H, sw, sb, Z, A, T);
}